// Round 7
// baseline (4806.934 us; speedup 1.0000x reference)
//
#include <hip/hip_runtime.h>
#include <math.h>

namespace {

constexpr int Bb = 8;
constexpr int Ss = 2048;
constexpr int Dd = 1024;
constexpr int D4 = Dd / 4;        // float4 per row
constexpr int NC = 256;           // s-chunks
constexpr int Sc2 = Ss / NC;      // 8 rows per chunk
constexpr int Tb = 256;
constexpr int BD = Bb * Dd;       // 8192 columns
constexpr float INV_SCALE = 0.03125f;  // 1/sqrt(1024)
constexpr float BIG = 3.0e38f;

// branch-free erf, Abramowitz-Stegun 7.1.26, |abs err| <= 1.5e-7
__device__ __forceinline__ float fast_erf(float z) {
  float az = fabsf(z);
  float t = __builtin_amdgcn_rcpf(fmaf(0.3275911f, az, 1.0f));
  float p = fmaf(1.061405429f, t, -1.453152027f);
  p = fmaf(p, t, 1.421413741f);
  p = fmaf(p, t, -0.284496736f);
  p = fmaf(p, t, 0.254829592f);
  p *= t;
  float e = __expf(-az * az);
  float r = fmaf(-p, e, 1.0f);
  return copysignf(r, z);
}
__device__ __forceinline__ float fm_act(float x) {
  return fmaf(0.5f * x, 1.0f + fast_erf(x * 0.70710678118654752f), 1.0f);
}

__device__ __forceinline__ float4 f4(float v) { return make_float4(v, v, v, v); }
__device__ __forceinline__ float4 add4(float4 a, float4 b) {
  return make_float4(a.x + b.x, a.y + b.y, a.z + b.z, a.w + b.w);
}
__device__ __forceinline__ float4 mul4(float4 a, float4 b) {
  return make_float4(a.x * b.x, a.y * b.y, a.z * b.z, a.w * b.w);
}
__device__ __forceinline__ float4 fma4(float4 a, float4 b, float4 c) {
  return make_float4(fmaf(a.x, b.x, c.x), fmaf(a.y, b.y, c.y), fmaf(a.z, b.z, c.z), fmaf(a.w, b.w, c.w));
}
__device__ __forceinline__ float4 min4(float4 a, float4 b) {
  return make_float4(fminf(a.x, b.x), fminf(a.y, b.y), fminf(a.z, b.z), fminf(a.w, b.w));
}
__device__ __forceinline__ float4 max4(float4 a, float4 b) {
  return make_float4(fmaxf(a.x, b.x), fmaxf(a.y, b.y), fmaxf(a.z, b.z), fmaxf(a.w, b.w));
}
__device__ __forceinline__ float4 fm4(float4 x) {
  return make_float4(fm_act(x.x), fm_act(x.y), fm_act(x.z), fm_act(x.w));
}
__device__ __forceinline__ float4 ld4(const float* p, size_t j4) {
  return reinterpret_cast<const float4*>(p)[j4];
}
__device__ __forceinline__ void st4(float* p, size_t j4, float4 v) {
  reinterpret_cast<float4*>(p)[j4] = v;
}
__device__ __forceinline__ float4 pexp4(float4 ei, float4 qf, float4 M) {
  return make_float4(__expf(fmaf(ei.x, qf.x, -M.x)), __expf(fmaf(ei.y, qf.y, -M.y)),
                     __expf(fmaf(ei.z, qf.z, -M.z)), __expf(fmaf(ei.w, qf.w, -M.w)));
}

__device__ __forceinline__ float blockSum(float v) {
  __shared__ float wsm[Tb / 64];
  for (int off = 32; off > 0; off >>= 1) v += __shfl_down(v, off, 64);
  const int lane = threadIdx.x & 63;
  const int w = threadIdx.x >> 6;
  __syncthreads();
  if (lane == 0) wsm[w] = v;
  __syncthreads();
  return wsm[0] + wsm[1] + wsm[2] + wsm[3];
}

// ---------- arg structs ----------
struct GA { const int* tok; float* X; float* cs; float* el; };
struct PA { const float* X; const float* qs; const float* off; float* pe; float* pmn; float* pmx; };
struct QA { const float* X; const float* qs; const float* ei; const float* Mv; float* ps; };
struct LA { float* X; const float* qs; const float* vs; const float* rs; const float* ml;
            const float* ei; const float* Mv; const float* rdv; const float* g; const float* bt;
            float* cs; float* el; float* xe; float* xn; float* xx; int wout; };

// Tail descriptor: deterministic last-K-blocks reduction folded into producer kernels.
struct TA {
  int* counter; int total; int kred; int kind;
  const float* cs0; const float* el0; float* off0; float* e0;   // scan E
  const float* cs1; const float* el1; float* off1; float* e1;   // scan D
  const float* pe0; const float* pmn0; const float* pmx0; float* ei0; float* Mv0;  // m8 E
  const float* pe1; const float* pmn1; const float* pmx1; float* ei1; float* Mv1;  // m8 D / xcomb
  const float* ps0; float* rdv0;                                 // r8 E
  const float* ps1; float* rdv1;                                 // r8 D
  float* ectx; float* v2out;
};

// ---- per-column tail work units (column j in [0,BD); fixed order => deterministic) ----
__device__ __forceinline__ void u_scan(const float* cs, const float* el, float* off,
                                       float* e, int j, float* lastv) {
  const int b = j >> 10, d = j & 1023;
  const size_t base = (size_t)b * NC * Dd + d;
  float run = 0.f, ee = 0.f;
  for (int c = 0; c < NC; ++c) {
    const size_t k = base + (size_t)c * Dd;
    float cv = cs[k];
    off[k] = run;
    ee += el[k] + run * cv;
    run += cv;
  }
  e[j] = ee;
  if (lastv) *lastv = run;
}

__device__ __forceinline__ void u_m8(const float* pe, const float* pmn, const float* pmx,
                                     float* ei, float* Mv, int j) {
  const int b = j >> 10, d = j & 1023;
  const size_t base = (size_t)b * NC * Dd + d;
  float ec = 0.f, mn = BIG, mx = 0.f;
  for (int c = 0; c < NC; ++c) {
    const size_t k = base + (size_t)c * Dd;
    ec += pe[k]; mn = fminf(mn, pmn[k]); mx = fmaxf(mx, pmx[k]);
  }
  const float e2 = ec * INV_SCALE;
  ei[j] = e2;
  Mv[j] = (ec >= 0.f) ? e2 * mx : e2 * mn;
}

__device__ __forceinline__ void u_xcomb(const float* pe, const float* pmn, const float* pmx,
                                        float ectxv, float* ei, float* Mv, int j) {
  const int b = j >> 10, d = j & 1023;
  const size_t base = (size_t)b * NC * Dd + d;
  float cq = 0.f, mn = BIG, mx = 0.f;
  for (int c = 0; c < NC; ++c) {
    const size_t k = base + (size_t)c * Dd;
    cq += pe[k]; mn = fminf(mn, pmn[k]); mx = fmaxf(mx, pmx[k]);
  }
  const float ec = fm_act(ectxv) * cq;
  const float e2 = ec * INV_SCALE;
  ei[j] = e2;
  Mv[j] = (ec >= 0.f) ? e2 * mx : e2 * mn;
}

__device__ __forceinline__ void u_sum(const float* ps, float* outv, int j, bool recip) {
  const int b = j >> 10, d = j & 1023;
  const size_t base = (size_t)b * NC * Dd + d;
  float s = 0.f;
  for (int c = 0; c < NC; ++c) s += ps[base + (size_t)c * Dd];
  outv[j] = recip ? 1.0f / s : s;
}

__device__ void run_tail(const TA& ta) {
  if (ta.kind == 0) return;
  __threadfence();                       // release our partial writes (device scope)
  __shared__ int rank_s;
  if (threadIdx.x == 0) {
    int old = atomicAdd(ta.counter, 1);
    int r = old - (ta.total - ta.kred);
    if (r >= 0) {
      while (__hip_atomic_load(ta.counter, __ATOMIC_ACQUIRE, __HIP_MEMORY_SCOPE_AGENT) < ta.total) {
        __builtin_amdgcn_s_sleep(8);
      }
    }
    rank_s = r;
  }
  __syncthreads();
  const int rank = rank_s;
  if (rank < 0) return;
  __threadfence();                       // acquire side
  const int u = rank * Tb + (int)threadIdx.x;
  switch (ta.kind) {
    case 1:  // scan E + scan D (post-gather)
      if (u < BD) u_scan(ta.cs0, ta.el0, ta.off0, ta.e0, u, nullptr);
      else u_scan(ta.cs1, ta.el1, ta.off1, ta.e1, u - BD, nullptr);
      break;
    case 2:  // m8 E + m8 D
      if (u < BD) u_m8(ta.pe0, ta.pmn0, ta.pmx0, ta.ei0, ta.Mv0, u);
      else u_m8(ta.pe1, ta.pmn1, ta.pmx1, ta.ei1, ta.Mv1, u - BD);
      break;
    case 3:  // r8 E + r8 D
      if (u < BD) u_sum(ta.ps0, ta.rdv0, u, true);
      else u_sum(ta.ps1, ta.rdv1, u - BD, true);
      break;
    case 4: {  // scan E (-> ectx) + dec-xe combine (uses ectx in register)
      float run;
      u_scan(ta.cs0, ta.el0, ta.off0, ta.e0, u, &run);
      ta.ectx[u] = run;
      u_xcomb(ta.pe1, ta.pmn1, ta.pmx1, run, ta.ei1, ta.Mv1, u);
      break;
    }
    case 5:  // m8 E (enc L2) + r8 D (cross 1)
      if (u < BD) u_m8(ta.pe0, ta.pmn0, ta.pmx0, ta.ei0, ta.Mv0, u);
      else u_sum(ta.ps1, ta.rdv1, u - BD, true);
      break;
    case 6: u_sum(ta.ps0, ta.rdv0, u, true); break;          // r8 E
    case 7: u_sum(ta.cs0, ta.v2out, u, false); break;        // v2 = colsum
    case 8: u_scan(ta.cs1, ta.el1, ta.off1, ta.e1, u, nullptr); break;  // scan D2
    case 9: u_m8(ta.pe1, ta.pmn1, ta.pmx1, ta.ei1, ta.Mv1, u); break;   // m8 D
    case 10: u_sum(ta.ps1, ta.rdv1, u, true); break;         // r8 D
    case 11: u_xcomb(ta.pe1, ta.pmn1, ta.pmx1, ta.ectx[u], ta.ei1, ta.Mv1, u); break;  // X2 combine
  }
}

// ---------- big-pass bodies ----------
__device__ __forceinline__ void body_p1(const PA& a) {
  const int t = threadIdx.x, c = blockIdx.x, b = blockIdx.y;
  const size_t idx = ((size_t)b * NC + c) * D4 + t;
  float4 run = ld4(a.off, idx);
  const float4 q4 = a.qs ? ld4(a.qs, (size_t)b * D4 + t) : f4(1.f);
  const float4* xp = reinterpret_cast<const float4*>(a.X) + ((size_t)(b * Ss + c * Sc2)) * D4 + t;
  float4 e = f4(0.f), mn = f4(BIG), mx = f4(0.f);
#pragma unroll
  for (int i = 0; i < Sc2; ++i) {
    float4 x = xp[(size_t)i * D4];
    run = add4(run, x);
    float4 qf = fm4(mul4(q4, x));
    float4 kf = fm4(run);
    e = fma4(qf, kf, e);
    mn = min4(mn, qf);
    mx = max4(mx, qf);
  }
  st4(a.pe, idx, e);
  st4(a.pmn, idx, mn);
  st4(a.pmx, idx, mx);
}

__device__ __forceinline__ void body_p2(const QA& a) {
  const int t = threadIdx.x, c = blockIdx.x, b = blockIdx.y;
  const size_t j4 = (size_t)b * D4 + t;
  const float4 q4 = a.qs ? ld4(a.qs, j4) : f4(1.f);
  const float4 e4 = ld4(a.ei, j4);
  const float4 M4 = ld4(a.Mv, j4);
  const float4* xp = reinterpret_cast<const float4*>(a.X) + ((size_t)(b * Ss + c * Sc2)) * D4 + t;
  float4 s = f4(0.f);
#pragma unroll
  for (int i = 0; i < Sc2; ++i) {
    float4 x = xp[(size_t)i * D4];
    float4 qf = fm4(mul4(q4, x));
    s = add4(s, pexp4(e4, qf, M4));
  }
  st4(a.ps, ((size_t)b * NC + c) * D4 + t, s);
}

// ---------- kernels: grid(NC, Bb, nz), 256 thr ----------
__global__ __launch_bounds__(Tb) void k_gather(GA a0, GA a1, const float* __restrict__ emb, TA ta) {
  const GA a = (blockIdx.z == 0) ? a0 : a1;
  const int t = threadIdx.x, c = blockIdx.x, b = blockIdx.y;
  const int* tp = a.tok + b * Ss + c * Sc2;
  float4* xp = reinterpret_cast<float4*>(a.X) + ((size_t)(b * Ss + c * Sc2)) * D4 + t;
  const float4* ep = reinterpret_cast<const float4*>(emb);
  float4 run = f4(0.f), e = f4(0.f);
#pragma unroll
  for (int i = 0; i < Sc2; ++i) {
    float4 v = ep[(size_t)tp[i] * D4 + t];
    xp[(size_t)i * D4] = v;
    run = add4(run, v);
    e = fma4(v, run, e);
  }
  const size_t idx = ((size_t)b * NC + c) * D4 + t;
  st4(a.cs, idx, run);
  st4(a.el, idx, e);
  run_tail(ta);
}

__global__ __launch_bounds__(Tb) void k_p1(PA a0, PA a1, TA ta) {
  body_p1((blockIdx.z == 0) ? a0 : a1);
  run_tail(ta);
}

__global__ __launch_bounds__(Tb) void k_p2(QA a0, QA a1, TA ta) {
  body_p2((blockIdx.z == 0) ? a0 : a1);
  run_tail(ta);
}

// z0: p1 work, z1: p2 work (overlaps enc-L2 p1 with dec cross-1 p2)
__global__ __launch_bounds__(Tb) void k_mix(PA pa, QA qa, TA ta) {
  if (blockIdx.z == 0) body_p1(pa); else body_p2(qa);
  run_tail(ta);
}

__global__ __launch_bounds__(Tb) void k_ln(LA a0, LA a1, TA ta) {
  const LA a = (blockIdx.z == 0) ? a0 : a1;
  __shared__ float red[Sc2][Tb];
  __shared__ float mu_s[Sc2], inv_s[Sc2];
  const int t = threadIdx.x, c = blockIdx.x, b = blockIdx.y;
  float4* xp = reinterpret_cast<float4*>(a.X) + ((size_t)(b * Ss + c * Sc2)) * D4 + t;
  const size_t j4 = (size_t)b * D4 + t;
  const float4 e4 = ld4(a.ei, j4), M4 = ld4(a.Mv, j4), rv4 = ld4(a.rdv, j4);
  const float4 q4 = a.qs ? ld4(a.qs, j4) : f4(1.f);
  const float4 vs4 = a.vs ? ld4(a.vs, j4) : f4(1.f);
  const float4 ml4 = a.ml ? ld4(a.ml, j4) : f4(1.f);
  const float4 rs4 = a.rs ? ld4(a.rs, j4) : f4(1.f);
  float4 vals[Sc2];
#pragma unroll
  for (int i = 0; i < Sc2; ++i) {
    float4 x = xp[(size_t)i * D4];
    float4 qf = fm4(mul4(q4, x));
    float4 p = mul4(pexp4(e4, qf, M4), rv4);
    float4 v = a.ml ? mul4(p, ml4) : mul4(p, mul4(vs4, x));
    float4 val = add4(v, mul4(rs4, x));
    vals[i] = val;
    red[i][t] = val.x + val.y + val.z + val.w;
  }
  __syncthreads();
  const int lane = t & 63, w = t >> 6;
#pragma unroll
  for (int rr = 0; rr < Sc2 / 4; ++rr) {
    const int row = w * (Sc2 / 4) + rr;
    float s = red[row][lane] + red[row][lane + 64] + red[row][lane + 128] + red[row][lane + 192];
    for (int off = 32; off > 0; off >>= 1) s += __shfl_down(s, off, 64);
    if (lane == 0) mu_s[row] = s * (1.0f / Dd);
  }
  __syncthreads();
#pragma unroll
  for (int i = 0; i < Sc2; ++i) {
    const float m = mu_s[i];
    float4 vv = vals[i];
    float aa = vv.x - m, b2 = vv.y - m, c2 = vv.z - m, d2 = vv.w - m;
    red[i][t] = aa * aa + b2 * b2 + c2 * c2 + d2 * d2;
  }
  __syncthreads();
#pragma unroll
  for (int rr = 0; rr < Sc2 / 4; ++rr) {
    const int row = w * (Sc2 / 4) + rr;
    float s = red[row][lane] + red[row][lane + 64] + red[row][lane + 128] + red[row][lane + 192];
    for (int off = 32; off > 0; off >>= 1) s += __shfl_down(s, off, 64);
    if (lane == 0) inv_s[row] = rsqrtf(s * (1.0f / Dd) + 1e-5f);
  }
  __syncthreads();
  const float4 g4 = ld4(a.g, t), b4 = ld4(a.bt, t);
  float4 run = f4(0.f), e = f4(0.f);
  float4 xs = f4(0.f), xmn = f4(BIG), xmx = f4(0.f);
#pragma unroll
  for (int i = 0; i < Sc2; ++i) {
    const float m = mu_s[i], inv = inv_s[i];
    float4 vv = vals[i];
    float4 y;
    y.x = fmaf((vv.x - m) * inv, g4.x, b4.x);
    y.y = fmaf((vv.y - m) * inv, g4.y, b4.y);
    y.z = fmaf((vv.z - m) * inv, g4.z, b4.z);
    y.w = fmaf((vv.w - m) * inv, g4.w, b4.w);
    if (a.wout) xp[(size_t)i * D4] = y;
    if (a.cs) {
      run = add4(run, y);
      if (a.el) e = fma4(y, run, e);
    }
    if (a.xe) {
      float4 qfy = fm4(y);
      xs = add4(xs, qfy);
      xmn = min4(xmn, qfy);
      xmx = max4(xmx, qfy);
    }
  }
  const size_t idx = ((size_t)b * NC + c) * D4 + t;
  if (a.cs) st4(a.cs, idx, run);
  if (a.el) st4(a.el, idx, e);
  if (a.xe) {
    st4(a.xe, idx, xs);
    st4(a.xn, idx, xmn);
    st4(a.xx, idx, xmx);
  }
  run_tail(ta);
}

// final: pooled[b,d] = sum_c csD; out = (pooled/S)@Wc + bc
__global__ __launch_bounds__(Tb) void k_final(const float* __restrict__ csD, const float* __restrict__ Wc,
    const float* __restrict__ bc, float* __restrict__ out) {
  const int b = blockIdx.x, t = threadIdx.x;
  float4 acc = f4(0.f);
  for (int c = 0; c < NC; ++c) acc = add4(acc, ld4(csD, ((size_t)(b * NC + c)) * D4 + t));
  float4 w0 = ld4(Wc, 2 * t), w1 = ld4(Wc, 2 * t + 1);
  float s0 = acc.x * w0.x + acc.y * w0.z + acc.z * w1.x + acc.w * w1.z;
  float s1 = acc.x * w0.y + acc.y * w0.w + acc.z * w1.y + acc.w * w1.w;
  s0 = blockSum(s0);
  s1 = blockSum(s1);
  if (t == 0) {
    out[b * 2 + 0] = s0 * (1.0f / Ss) + bc[0];
    out[b * 2 + 1] = s1 * (1.0f / Ss) + bc[1];
  }
}

}  // namespace

extern "C" void kernel_launch(void* const* d_in, const int* in_sizes, int n_in,
                              void* d_out, int out_size, void* d_ws, size_t ws_size,
                              hipStream_t stream) {
  (void)in_sizes; (void)n_in; (void)out_size; (void)ws_size;
  const int* src = (const int*)d_in[0];
  const int* trg = (const int*)d_in[1];
  const float* emb = (const float*)d_in[2];
  const float* enc_g = (const float*)d_in[3];
  const float* enc_b = (const float*)d_in[4];
  const float* dec_ng = (const float*)d_in[5];
  const float* dec_nb = (const float*)d_in[6];
  const float* dec_tg = (const float*)d_in[7];
  const float* dec_tb = (const float*)d_in[8];
  const float* Wc = (const float*)d_in[9];
  const float* bc = (const float*)d_in[10];
  float* out = (float*)d_out;

  float* ws = (float*)d_ws;
  const size_t TEN = (size_t)Bb * Ss * Dd;
  const size_t MM = (size_t)Bb * NC * Dd;
  float* A0 = ws;
  float* A1 = A0 + TEN;
  float* p = A1 + TEN;
  float* csE = p; p += MM;  float* elE = p; p += MM;  float* offE = p; p += MM;
  float* peE = p; p += MM;  float* pmnE = p; p += MM; float* pmxE = p; p += MM;
  float* psE = p; p += MM;
  float* csD = p; p += MM;  float* elD = p; p += MM;  float* offD = p; p += MM;
  float* peD = p; p += MM;  float* pmnD = p; p += MM; float* pmxD = p; p += MM;
  float* psD = p; p += MM;
  float* e0E = p; p += BD;  float* e1E = p; p += BD;
  float* e0D = p; p += BD;  float* e1D = p; p += BD;
  float* eiE = p; p += BD;  float* MvE = p; p += BD;  float* rdvE = p; p += BD;
  float* eiD = p; p += BD;  float* MvD = p; p += BD;  float* rdvD = p; p += BD;
  float* ectx = p; p += BD; float* v2 = p; p += BD;
  int* cnt = reinterpret_cast<int*>(p);

  hipMemsetAsync(cnt, 0, 14 * sizeof(int), stream);

  const dim3 g2(NC, Bb, 2), g1(NC, Bb, 1);
  const int T2 = NC * Bb * 2, T1 = NC * Bb;

  auto mkTA = [&](int idx, int total, int kred, int kind) {
    TA ta{}; ta.counter = cnt + idx; ta.total = total; ta.kred = kred; ta.kind = kind;
    return ta;
  };

  // L1: gather enc||dec; tail: scan E + scan D -> offE/e0E, offD/e0D
  {
    TA ta = mkTA(0, T2, 64, 1);
    ta.cs0 = csE; ta.el0 = elE; ta.off0 = offE; ta.e0 = e0E;
    ta.cs1 = csD; ta.el1 = elD; ta.off1 = offD; ta.e1 = e0D;
    k_gather<<<g2, Tb, 0, stream>>>(GA{src, A0, csE, elE}, GA{trg, A1, csD, elD}, emb, ta);
  }
  // L2: p1 L1 enc||dec; tail: m8 E + m8 D -> ei/Mv
  {
    TA ta = mkTA(1, T2, 64, 2);
    ta.pe0 = peE; ta.pmn0 = pmnE; ta.pmx0 = pmxE; ta.ei0 = eiE; ta.Mv0 = MvE;
    ta.pe1 = peD; ta.pmn1 = pmnD; ta.pmx1 = pmxD; ta.ei1 = eiD; ta.Mv1 = MvD;
    k_p1<<<g2, Tb, 0, stream>>>(PA{A0, e0E, offE, peE, pmnE, pmxE}, PA{A1, e0D, offD, peD, pmnD, pmxD}, ta);
  }
  // L3: p2 L1 enc||dec; tail: r8 E + r8 D -> rdv
  {
    TA ta = mkTA(2, T2, 64, 3);
    ta.ps0 = psE; ta.rdv0 = rdvE; ta.ps1 = psD; ta.rdv1 = rdvD;
    k_p2<<<g2, Tb, 0, stream>>>(QA{A0, e0E, eiE, MvE, psE}, QA{A1, e0D, eiD, MvD, psD}, ta);
  }
  // L4: ln L1 enc (emits csE/elE) || dec self-ln (emits xe->peD..);
  // tail: scan E2 -> offE/e1E/ectx, then dec-xe combine -> eiD/MvD (cross-1)
  {
    TA ta = mkTA(3, T2, 32, 4);
    ta.cs0 = csE; ta.el0 = elE; ta.off0 = offE; ta.e0 = e1E; ta.ectx = ectx;
    ta.pe1 = peD; ta.pmn1 = pmnD; ta.pmx1 = pmxD; ta.ei1 = eiD; ta.Mv1 = MvD;
    k_ln<<<g2, Tb, 0, stream>>>(
        LA{A0, e0E, e0E, e0E, nullptr, eiE, MvE, rdvE, enc_g, enc_b, csE, elE, nullptr, nullptr, nullptr, 1},
        LA{A1, e0D, e0D, e0D, nullptr, eiD, MvD, rdvD, dec_ng, dec_nb, nullptr, nullptr, peD, pmnD, pmxD, 1}, ta);
  }
  // L5: p1 enc-L2 || p2 dec-cross1; tail: m8 E -> eiE/MvE, r8 D -> rdvD
  {
    TA ta = mkTA(4, T2, 64, 5);
    ta.pe0 = peE; ta.pmn0 = pmnE; ta.pmx0 = pmxE; ta.ei0 = eiE; ta.Mv0 = MvE;
    ta.ps1 = psD; ta.rdv1 = rdvD;
    k_mix<<<g2, Tb, 0, stream>>>(PA{A0, nullptr, offE, peE, pmnE, pmxE}, QA{A1, nullptr, eiD, MvD, psD}, ta);
  }
  // L6: p2 enc-L2; tail: r8 E -> rdvE
  {
    TA ta = mkTA(5, T1, 32, 6);
    ta.ps0 = psE; ta.rdv0 = rdvE;
    k_p2<<<g1, Tb, 0, stream>>>(QA{A0, nullptr, eiE, MvE, psE}, QA{A0, nullptr, eiE, MvE, psE}, ta);
  }
  // L7: ln enc-L2 (wout=0, emits csE); tail: v2 = colsum(csE)
  {
    TA ta = mkTA(6, T1, 32, 7);
    ta.cs0 = csE; ta.v2out = v2;
    k_ln<<<g1, Tb, 0, stream>>>(
        LA{A0, nullptr, e1E, nullptr, nullptr, eiE, MvE, rdvE, enc_g + Dd, enc_b + Dd, csE, nullptr, nullptr, nullptr, nullptr, 0},
        LA{A0, nullptr, e1E, nullptr, nullptr, eiE, MvE, rdvE, enc_g + Dd, enc_b + Dd, csE, nullptr, nullptr, nullptr, nullptr, 0}, ta);
  }
  // L8: ln dec-cross1 (ml=v2, writes x1, emits csD/elD); tail: scan D2 -> offD/e1D
  {
    TA ta = mkTA(7, T1, 32, 8);
    ta.cs1 = csD; ta.el1 = elD; ta.off1 = offD; ta.e1 = e1D;
    k_ln<<<g1, Tb, 0, stream>>>(
        LA{A1, nullptr, nullptr, nullptr, v2, eiD, MvD, rdvD, dec_tg, dec_tb, csD, elD, nullptr, nullptr, nullptr, 1},
        LA{A1, nullptr, nullptr, nullptr, v2, eiD, MvD, rdvD, dec_tg, dec_tb, csD, elD, nullptr, nullptr, nullptr, 1}, ta);
  }
  // L9: p1 dec-L2; tail: m8 D -> eiD/MvD
  {
    TA ta = mkTA(8, T1, 32, 9);
    ta.pe1 = peD; ta.pmn1 = pmnD; ta.pmx1 = pmxD; ta.ei1 = eiD; ta.Mv1 = MvD;
    k_p1<<<g1, Tb, 0, stream>>>(PA{A1, nullptr, offD, peD, pmnD, pmxD}, PA{A1, nullptr, offD, peD, pmnD, pmxD}, ta);
  }
  // L10: p2 dec-L2; tail: r8 D -> rdvD
  {
    TA ta = mkTA(9, T1, 32, 10);
    ta.ps1 = psD; ta.rdv1 = rdvD;
    k_p2<<<g1, Tb, 0, stream>>>(QA{A1, nullptr, eiD, MvD, psD}, QA{A1, nullptr, eiD, MvD, psD}, ta);
  }
  // L11: ln dec-L2 (vs=e1D, writes q1, emits xe); tail: X2 combine (ectx) -> eiD/MvD
  {
    TA ta = mkTA(10, T1, 32, 11);
    ta.pe1 = peD; ta.pmn1 = pmnD; ta.pmx1 = pmxD; ta.ei1 = eiD; ta.Mv1 = MvD; ta.ectx = ectx;
    k_ln<<<g1, Tb, 0, stream>>>(
        LA{A1, nullptr, e1D, nullptr, nullptr, eiD, MvD, rdvD, dec_ng + Dd, dec_nb + Dd, nullptr, nullptr, peD, pmnD, pmxD, 1},
        LA{A1, nullptr, e1D, nullptr, nullptr, eiD, MvD, rdvD, dec_ng + Dd, dec_nb + Dd, nullptr, nullptr, peD, pmnD, pmxD, 1}, ta);
  }
  // L12: p2 dec-cross2; tail: r8 D -> rdvD
  {
    TA ta = mkTA(11, T1, 32, 10);
    ta.ps1 = psD; ta.rdv1 = rdvD;
    k_p2<<<g1, Tb, 0, stream>>>(QA{A1, nullptr, eiD, MvD, psD}, QA{A1, nullptr, eiD, MvD, psD}, ta);
  }
  // L13: ln dec-cross2 (wout=0, ml=v2, emits csD); no tail (k_final reduces csD)
  {
    TA ta = mkTA(12, T1, 32, 0);
    k_ln<<<g1, Tb, 0, stream>>>(
        LA{A1, nullptr, nullptr, nullptr, v2, eiD, MvD, rdvD, dec_tg + Dd, dec_tb + Dd, csD, nullptr, nullptr, nullptr, nullptr, 0},
        LA{A1, nullptr, nullptr, nullptr, v2, eiD, MvD, rdvD, dec_tg + Dd, dec_tb + Dd, csD, nullptr, nullptr, nullptr, nullptr, 0}, ta);
  }
  // L14: final
  k_final<<<Bb, Tb, 0, stream>>>(csD, Wc, bc, out);
}

// Round 8
// 464.435 us; speedup vs baseline: 10.3501x; 10.3501x over previous
//
#include <hip/hip_runtime.h>
#include <math.h>

namespace {

constexpr int Bb = 8;
constexpr int Ss = 2048;
constexpr int Dd = 1024;
constexpr int D4 = Dd / 4;        // float4 per row
constexpr int NC = 256;           // s-chunks
constexpr int Sc2 = Ss / NC;      // 8 rows per chunk
constexpr int Tb = 256;
constexpr int SEG = 8;            // segments per column in tiny reducers
constexpr int CPS = NC / SEG;     // 32 chunks per segment
constexpr float INV_SCALE = 0.03125f;  // 1/sqrt(1024)
constexpr float BIG = 3.0e38f;

// branch-free erf, Abramowitz-Stegun 7.1.26, |abs err| <= 1.5e-7
__device__ __forceinline__ float fast_erf(float z) {
  float az = fabsf(z);
  float t = __builtin_amdgcn_rcpf(fmaf(0.3275911f, az, 1.0f));
  float p = fmaf(1.061405429f, t, -1.453152027f);
  p = fmaf(p, t, 1.421413741f);
  p = fmaf(p, t, -0.284496736f);
  p = fmaf(p, t, 0.254829592f);
  p *= t;
  float e = __expf(-az * az);
  float r = fmaf(-p, e, 1.0f);
  return copysignf(r, z);
}
// gelu(x, exact) + 1
__device__ __forceinline__ float fm_act(float x) {
  return fmaf(0.5f * x, 1.0f + fast_erf(x * 0.70710678118654752f), 1.0f);
}

__device__ __forceinline__ float4 f4(float v) { return make_float4(v, v, v, v); }
__device__ __forceinline__ float4 add4(float4 a, float4 b) {
  return make_float4(a.x + b.x, a.y + b.y, a.z + b.z, a.w + b.w);
}
__device__ __forceinline__ float4 mul4(float4 a, float4 b) {
  return make_float4(a.x * b.x, a.y * b.y, a.z * b.z, a.w * b.w);
}
__device__ __forceinline__ float4 fma4(float4 a, float4 b, float4 c) {
  return make_float4(fmaf(a.x, b.x, c.x), fmaf(a.y, b.y, c.y), fmaf(a.z, b.z, c.z), fmaf(a.w, b.w, c.w));
}
__device__ __forceinline__ float4 min4(float4 a, float4 b) {
  return make_float4(fminf(a.x, b.x), fminf(a.y, b.y), fminf(a.z, b.z), fminf(a.w, b.w));
}
__device__ __forceinline__ float4 max4(float4 a, float4 b) {
  return make_float4(fmaxf(a.x, b.x), fmaxf(a.y, b.y), fmaxf(a.z, b.z), fmaxf(a.w, b.w));
}
__device__ __forceinline__ float4 fm4(float4 x) {
  return make_float4(fm_act(x.x), fm_act(x.y), fm_act(x.z), fm_act(x.w));
}
__device__ __forceinline__ float4 ld4(const float* p, size_t j4) {
  return reinterpret_cast<const float4*>(p)[j4];
}
__device__ __forceinline__ void st4(float* p, size_t j4, float4 v) {
  reinterpret_cast<float4*>(p)[j4] = v;
}
__device__ __forceinline__ float4 pexp4(float4 ei, float4 qf, float4 M) {
  return make_float4(__expf(fmaf(ei.x, qf.x, -M.x)), __expf(fmaf(ei.y, qf.y, -M.y)),
                     __expf(fmaf(ei.z, qf.z, -M.z)), __expf(fmaf(ei.w, qf.w, -M.w)));
}

__device__ __forceinline__ float blockSum(float v) {
  __shared__ float wsm[Tb / 64];
  for (int off = 32; off > 0; off >>= 1) v += __shfl_down(v, off, 64);
  const int lane = threadIdx.x & 63;
  const int w = threadIdx.x >> 6;
  __syncthreads();
  if (lane == 0) wsm[w] = v;
  __syncthreads();
  return wsm[0] + wsm[1] + wsm[2] + wsm[3];
}

// ---------- arg structs (z-mergeable kernels pick by blockIdx.z) ----------
struct GA { const int* tok; float* X; float* cs; float* el; };
struct SA { const float* cs; const float* el; float* off; float* e; float* last; };
struct PA { const float* X; const float* qs; const float* off; float* pe; float* pmn; float* pmx; };
struct MA { const float* pe; const float* pmn; const float* pmx; const float* k2; float* ei; float* Mv; };
struct QA { const float* X; const float* qs; const float* ei; const float* Mv; float* ps; };
struct RA { const float* pp; float* outv; int recip; };
struct LA { float* X; const float* qs; const float* vs; const float* rs; const float* ml;
            const float* ei; const float* Mv; const float* rdv; const float* g; const float* bt;
            float* cs; float* el; float* xe; float* xn; float* xx; int wout; };

// ---------- big column-pass kernels: grid(NC, B, nz), 256 thr, thread t = float4 at d=4t ----------

// gather emb rows + chunk colsums + local gds partial
__global__ __launch_bounds__(Tb) void k_gather(GA a0, GA a1, const float* __restrict__ emb) {
  const GA a = (blockIdx.z == 0) ? a0 : a1;
  const int t = threadIdx.x, c = blockIdx.x, b = blockIdx.y;
  const int* tp = a.tok + b * Ss + c * Sc2;
  float4* xp = reinterpret_cast<float4*>(a.X) + ((size_t)(b * Ss + c * Sc2)) * D4 + t;
  const float4* ep = reinterpret_cast<const float4*>(emb);
  float4 run = f4(0.f), e = f4(0.f);
#pragma unroll
  for (int i = 0; i < Sc2; ++i) {
    float4 v = ep[(size_t)tp[i] * D4 + t];
    xp[(size_t)i * D4] = v;
    run = add4(run, v);
    e = fma4(v, run, e);
  }
  const size_t idx = ((size_t)b * NC + c) * D4 + t;
  st4(a.cs, idx, run);
  st4(a.el, idx, e);
}

// self-attn p1: ctx from off + running sum; partial ecol & qf min/max per chunk
__global__ __launch_bounds__(Tb) void k_p1(PA a0, PA a1) {
  const PA a = (blockIdx.z == 0) ? a0 : a1;
  const int t = threadIdx.x, c = blockIdx.x, b = blockIdx.y;
  const size_t idx = ((size_t)b * NC + c) * D4 + t;
  float4 run = ld4(a.off, idx);
  const float4 q4 = a.qs ? ld4(a.qs, (size_t)b * D4 + t) : f4(1.f);
  const float4* xp = reinterpret_cast<const float4*>(a.X) + ((size_t)(b * Ss + c * Sc2)) * D4 + t;
  float4 e = f4(0.f), mn = f4(BIG), mx = f4(0.f);
#pragma unroll
  for (int i = 0; i < Sc2; ++i) {
    float4 x = xp[(size_t)i * D4];
    run = add4(run, x);
    float4 qf = fm4(mul4(q4, x));
    float4 kf = fm4(run);
    e = fma4(qf, kf, e);
    mn = min4(mn, qf);
    mx = max4(mx, qf);
  }
  st4(a.pe, idx, e);
  st4(a.pmn, idx, mn);
  st4(a.pmx, idx, mx);
}

// p2: partial sumexp per chunk (self [qs] and cross [qs=null])
__global__ __launch_bounds__(Tb) void k_p2(QA a0, QA a1) {
  const QA a = (blockIdx.z == 0) ? a0 : a1;
  const int t = threadIdx.x, c = blockIdx.x, b = blockIdx.y;
  const size_t j4 = (size_t)b * D4 + t;
  const float4 q4 = a.qs ? ld4(a.qs, j4) : f4(1.f);
  const float4 e4 = ld4(a.ei, j4);
  const float4 M4 = ld4(a.Mv, j4);
  const float4* xp = reinterpret_cast<const float4*>(a.X) + ((size_t)(b * Ss + c * Sc2)) * D4 + t;
  float4 s = f4(0.f);
#pragma unroll
  for (int i = 0; i < Sc2; ++i) {
    float4 x = xp[(size_t)i * D4];
    float4 qf = fm4(mul4(q4, x));
    s = add4(s, pexp4(e4, qf, M4));
  }
  st4(a.ps, ((size_t)b * NC + c) * D4 + t, s);
}

// fused softmax-apply + residual + LayerNorm (in place, store optional via wout),
// optional chunk colsum/gds partials, optional cross-attn qf partials of the output.
__global__ __launch_bounds__(Tb) void k_ln(LA a0, LA a1) {
  const LA a = (blockIdx.z == 0) ? a0 : a1;
  __shared__ float red[Sc2][Tb];
  __shared__ float mu_s[Sc2], inv_s[Sc2];
  const int t = threadIdx.x, c = blockIdx.x, b = blockIdx.y;
  float4* xp = reinterpret_cast<float4*>(a.X) + ((size_t)(b * Ss + c * Sc2)) * D4 + t;
  const size_t j4 = (size_t)b * D4 + t;
  const float4 e4 = ld4(a.ei, j4), M4 = ld4(a.Mv, j4), rv4 = ld4(a.rdv, j4);
  const float4 q4 = a.qs ? ld4(a.qs, j4) : f4(1.f);
  const float4 vs4 = a.vs ? ld4(a.vs, j4) : f4(1.f);
  const float4 ml4 = a.ml ? ld4(a.ml, j4) : f4(1.f);
  const float4 rs4 = a.rs ? ld4(a.rs, j4) : f4(1.f);
  float4 vals[Sc2];
#pragma unroll
  for (int i = 0; i < Sc2; ++i) {
    float4 x = xp[(size_t)i * D4];
    float4 qf = fm4(mul4(q4, x));
    float4 p = mul4(pexp4(e4, qf, M4), rv4);
    float4 v = a.ml ? mul4(p, ml4) : mul4(p, mul4(vs4, x));
    float4 val = add4(v, mul4(rs4, x));
    vals[i] = val;
    red[i][t] = val.x + val.y + val.z + val.w;
  }
  __syncthreads();
  const int lane = t & 63, w = t >> 6;
#pragma unroll
  for (int rr = 0; rr < Sc2 / 4; ++rr) {
    const int row = w * (Sc2 / 4) + rr;
    float s = red[row][lane] + red[row][lane + 64] + red[row][lane + 128] + red[row][lane + 192];
    for (int off = 32; off > 0; off >>= 1) s += __shfl_down(s, off, 64);
    if (lane == 0) mu_s[row] = s * (1.0f / Dd);
  }
  __syncthreads();
#pragma unroll
  for (int i = 0; i < Sc2; ++i) {
    const float m = mu_s[i];
    float4 vv = vals[i];
    float aa = vv.x - m, b2 = vv.y - m, c2 = vv.z - m, d2 = vv.w - m;
    red[i][t] = aa * aa + b2 * b2 + c2 * c2 + d2 * d2;
  }
  __syncthreads();
#pragma unroll
  for (int rr = 0; rr < Sc2 / 4; ++rr) {
    const int row = w * (Sc2 / 4) + rr;
    float s = red[row][lane] + red[row][lane + 64] + red[row][lane + 128] + red[row][lane + 192];
    for (int off = 32; off > 0; off >>= 1) s += __shfl_down(s, off, 64);
    if (lane == 0) inv_s[row] = rsqrtf(s * (1.0f / Dd) + 1e-5f);
  }
  __syncthreads();
  const float4 g4 = ld4(a.g, t), b4 = ld4(a.bt, t);
  float4 run = f4(0.f), e = f4(0.f);
  float4 xs = f4(0.f), xmn = f4(BIG), xmx = f4(0.f);
#pragma unroll
  for (int i = 0; i < Sc2; ++i) {
    const float m = mu_s[i], inv = inv_s[i];
    float4 vv = vals[i];
    float4 y;
    y.x = fmaf((vv.x - m) * inv, g4.x, b4.x);
    y.y = fmaf((vv.y - m) * inv, g4.y, b4.y);
    y.z = fmaf((vv.z - m) * inv, g4.z, b4.z);
    y.w = fmaf((vv.w - m) * inv, g4.w, b4.w);
    if (a.wout) xp[(size_t)i * D4] = y;
    if (a.cs) {
      run = add4(run, y);
      if (a.el) e = fma4(y, run, e);
    }
    if (a.xe) {
      float4 qfy = fm4(y);
      xs = add4(xs, qfy);
      xmn = min4(xmn, qfy);
      xmx = max4(xmx, qfy);
    }
  }
  const size_t idx = ((size_t)b * NC + c) * D4 + t;
  if (a.cs) st4(a.cs, idx, run);
  if (a.el) st4(a.el, idx, e);
  if (a.xe) {
    st4(a.xe, idx, xs);
    st4(a.xn, idx, xmn);
    st4(a.xx, idx, xmx);
  }
}

// ---------- tiny reducers: grid(BD/32, 1, nz), 256 thr = 32 columns x 8 segments ----------

__global__ __launch_bounds__(Tb) void t_scan8(SA a0, SA a1) {
  const SA a = (blockIdx.z == 0) ? a0 : a1;
  __shared__ float lds[SEG][32];
  const int tid = threadIdx.x;
  const int jl = tid & 31, seg = tid >> 5;
  const int j = blockIdx.x * 32 + jl;
  const int b = j >> 10, d = j & 1023;
  const size_t base = (size_t)b * NC * Dd + d;
  float s = 0.f;
#pragma unroll 8
  for (int i = 0; i < CPS; ++i) s += a.cs[base + (size_t)(seg * CPS + i) * Dd];
  lds[seg][jl] = s;
  __syncthreads();
  float o = 0.f;
#pragma unroll
  for (int g2 = 0; g2 < SEG; ++g2) { float v = lds[g2][jl]; o += (g2 < seg) ? v : 0.f; }
  __syncthreads();
  float run = o, e = 0.f;
#pragma unroll 8
  for (int i = 0; i < CPS; ++i) {
    const size_t k = base + (size_t)(seg * CPS + i) * Dd;
    float cv = a.cs[k];
    a.off[k] = run;
    e += a.el[k] + run * cv;
    run += cv;
  }
  lds[seg][jl] = e;
  __syncthreads();
  if (seg == 0) {
    float et = 0.f;
#pragma unroll
    for (int g2 = 0; g2 < SEG; ++g2) et += lds[g2][jl];
    a.e[j] = et;
  }
  if (a.last && seg == SEG - 1) a.last[j] = run;
}

// reduce p1/xq partials -> ei, Mv. k2 non-null => cross (ec = fm(k2)*colsum)
__global__ __launch_bounds__(Tb) void t_m8(MA a0, MA a1) {
  const MA a = (blockIdx.z == 0) ? a0 : a1;
  __shared__ float le[SEG][32], lmn[SEG][32], lmx[SEG][32];
  const int tid = threadIdx.x;
  const int jl = tid & 31, seg = tid >> 5;
  const int j = blockIdx.x * 32 + jl;
  const int b = j >> 10, d = j & 1023;
  const size_t base = (size_t)b * NC * Dd + d;
  float ec = 0.f, mn = BIG, mx = 0.f;
#pragma unroll 8
  for (int i = 0; i < CPS; ++i) {
    const size_t k = base + (size_t)(seg * CPS + i) * Dd;
    ec += a.pe[k];
    mn = fminf(mn, a.pmn[k]);
    mx = fmaxf(mx, a.pmx[k]);
  }
  le[seg][jl] = ec; lmn[seg][jl] = mn; lmx[seg][jl] = mx;
  __syncthreads();
  if (seg == 0) {
#pragma unroll
    for (int g2 = 1; g2 < SEG; ++g2) {
      ec += le[g2][jl];
      mn = fminf(mn, lmn[g2][jl]);
      mx = fmaxf(mx, lmx[g2][jl]);
    }
    if (a.k2) ec *= fm_act(a.k2[j]);
    const float e2 = ec * INV_SCALE;
    a.ei[j] = e2;
    a.Mv[j] = (ec >= 0.f) ? e2 * mx : e2 * mn;
  }
}

// reduce partials -> sum (recip=0) or 1/sum (recip=1)
__global__ __launch_bounds__(Tb) void t_red8(RA a0, RA a1) {
  const RA a = (blockIdx.z == 0) ? a0 : a1;
  __shared__ float lds[SEG][32];
  const int tid = threadIdx.x;
  const int jl = tid & 31, seg = tid >> 5;
  const int j = blockIdx.x * 32 + jl;
  const int b = j >> 10, d = j & 1023;
  const size_t base = (size_t)b * NC * Dd + d;
  float s = 0.f;
#pragma unroll 8
  for (int i = 0; i < CPS; ++i) s += a.pp[base + (size_t)(seg * CPS + i) * Dd];
  lds[seg][jl] = s;
  __syncthreads();
  if (seg == 0) {
#pragma unroll
    for (int g2 = 1; g2 < SEG; ++g2) s += lds[g2][jl];
    a.outv[j] = a.recip ? 1.0f / s : s;
  }
}

// final: pooled[b,d] = sum_c csD[b,c,d]; out = (pooled/S)@Wc + bc
__global__ __launch_bounds__(Tb) void k_final(const float* __restrict__ csD, const float* __restrict__ Wc,
    const float* __restrict__ bc, float* __restrict__ out) {
  const int b = blockIdx.x, t = threadIdx.x;
  float4 acc = f4(0.f);
  for (int c = 0; c < NC; ++c) acc = add4(acc, ld4(csD, ((size_t)(b * NC + c)) * D4 + t));
  float4 w0 = ld4(Wc, 2 * t), w1 = ld4(Wc, 2 * t + 1);
  float s0 = acc.x * w0.x + acc.y * w0.z + acc.z * w1.x + acc.w * w1.z;
  float s1 = acc.x * w0.y + acc.y * w0.w + acc.z * w1.y + acc.w * w1.w;
  s0 = blockSum(s0);
  s1 = blockSum(s1);
  if (t == 0) {
    out[b * 2 + 0] = s0 * (1.0f / Ss) + bc[0];
    out[b * 2 + 1] = s1 * (1.0f / Ss) + bc[1];
  }
}

}  // namespace

extern "C" void kernel_launch(void* const* d_in, const int* in_sizes, int n_in,
                              void* d_out, int out_size, void* d_ws, size_t ws_size,
                              hipStream_t stream) {
  (void)in_sizes; (void)n_in; (void)out_size; (void)ws_size;
  const int* src = (const int*)d_in[0];
  const int* trg = (const int*)d_in[1];
  const float* emb = (const float*)d_in[2];
  const float* enc_g = (const float*)d_in[3];
  const float* enc_b = (const float*)d_in[4];
  const float* dec_ng = (const float*)d_in[5];
  const float* dec_nb = (const float*)d_in[6];
  const float* dec_tg = (const float*)d_in[7];
  const float* dec_tb = (const float*)d_in[8];
  const float* Wc = (const float*)d_in[9];
  const float* bc = (const float*)d_in[10];
  float* out = (float*)d_out;

  float* ws = (float*)d_ws;
  const size_t TEN = (size_t)Bb * Ss * Dd;      // 16.7M floats
  const size_t MM = (size_t)Bb * NC * Dd;       // 2.1M floats
  float* A0 = ws;                                // encoder tensor
  float* A1 = A0 + TEN;                          // decoder tensor
  float* p = A1 + TEN;
  float* csE = p; p += MM;  float* elE = p; p += MM;  float* offE = p; p += MM;
  float* peE = p; p += MM;  float* pmnE = p; p += MM; float* pmxE = p; p += MM;
  float* psE = p; p += MM;
  float* csD = p; p += MM;  float* elD = p; p += MM;  float* offD = p; p += MM;
  float* peD = p; p += MM;  float* pmnD = p; p += MM; float* pmxD = p; p += MM;
  float* psD = p; p += MM;
  const int BD = Bb * Dd;
  float* e0E = p; p += BD;  float* e1E = p; p += BD;
  float* e0D = p; p += BD;  float* e1D = p; p += BD;
  float* eiE = p; p += BD;  float* MvE = p; p += BD;  float* rdvE = p; p += BD;
  float* eiD = p; p += BD;  float* MvD = p; p += BD;  float* rdvD = p; p += BD;
  float* ectx = p; p += BD; float* v2 = p; p += BD;

  const dim3 g2(NC, Bb, 2), g1(NC, Bb, 1);
  const dim3 t2(BD / 32, 1, 2), t1(BD / 32, 1, 1);

  // ===== L1 stage: encoder L1 || decoder L1 self (independent, z-merged) =====
  k_gather<<<g2, Tb, 0, stream>>>(GA{src, A0, csE, elE}, GA{trg, A1, csD, elD}, emb);
  t_scan8<<<t2, Tb, 0, stream>>>(SA{csE, elE, offE, e0E, nullptr}, SA{csD, elD, offD, e0D, nullptr});
  k_p1<<<g2, Tb, 0, stream>>>(PA{A0, e0E, offE, peE, pmnE, pmxE}, PA{A1, e0D, offD, peD, pmnD, pmxD});
  t_m8<<<t2, Tb, 0, stream>>>(MA{peE, pmnE, pmxE, nullptr, eiE, MvE}, MA{peD, pmnD, pmxD, nullptr, eiD, MvD});
  k_p2<<<g2, Tb, 0, stream>>>(QA{A0, e0E, eiE, MvE, psE}, QA{A1, e0D, eiD, MvD, psD});
  t_red8<<<t2, Tb, 0, stream>>>(RA{psE, rdvE, 1}, RA{psD, rdvD, 1});
  // enc L1 LN (emits cs/el for enc L2 scan); dec L1 self LN (emits cross-attn qf partials)
  k_ln<<<g2, Tb, 0, stream>>>(
      LA{A0, e0E, e0E, e0E, nullptr, eiE, MvE, rdvE, enc_g, enc_b, csE, elE, nullptr, nullptr, nullptr, 1},
      LA{A1, e0D, e0D, e0D, nullptr, eiD, MvD, rdvD, dec_ng, dec_nb, nullptr, nullptr, peD, pmnD, pmxD, 1});

  // ===== enc L2 scan (produces ectx, the only cross-attn K) =====
  t_scan8<<<t1, Tb, 0, stream>>>(SA{csE, elE, offE, e1E, ectx}, SA{csE, elE, offE, e1E, ectx});
  k_p1<<<g1, Tb, 0, stream>>>(PA{A0, nullptr, offE, peE, pmnE, pmxE}, PA{A0, nullptr, offE, peE, pmnE, pmxE});

  // ===== enc L2 self || dec cross-1 (z-merged) =====
  t_m8<<<t2, Tb, 0, stream>>>(MA{peE, pmnE, pmxE, nullptr, eiE, MvE}, MA{peD, pmnD, pmxD, ectx, eiD, MvD});
  k_p2<<<g2, Tb, 0, stream>>>(QA{A0, nullptr, eiE, MvE, psE}, QA{A1, nullptr, eiD, MvD, psD});
  t_red8<<<t2, Tb, 0, stream>>>(RA{psE, rdvE, 1}, RA{psD, rdvD, 1});
  // enc L2 LN: output tensor never read -> skip store; emit only colsum partials (v2)
  k_ln<<<g1, Tb, 0, stream>>>(
      LA{A0, nullptr, e1E, nullptr, nullptr, eiE, MvE, rdvE, enc_g + Dd, enc_b + Dd, csE, nullptr, nullptr, nullptr, nullptr, 0},
      LA{A0, nullptr, e1E, nullptr, nullptr, eiE, MvE, rdvE, enc_g + Dd, enc_b + Dd, csE, nullptr, nullptr, nullptr, nullptr, 0});
  t_red8<<<t1, Tb, 0, stream>>>(RA{csE, v2, 0}, RA{csE, v2, 0});  // v2 = colsum(enc_out)

  // ===== dec cross-1 LN (needs v2) =====
  k_ln<<<g1, Tb, 0, stream>>>(
      LA{A1, nullptr, nullptr, nullptr, v2, eiD, MvD, rdvD, dec_tg, dec_tb, csD, elD, nullptr, nullptr, nullptr, 1},
      LA{A1, nullptr, nullptr, nullptr, v2, eiD, MvD, rdvD, dec_tg, dec_tb, csD, elD, nullptr, nullptr, nullptr, 1});

  // ===== dec L2 self =====
  t_scan8<<<t1, Tb, 0, stream>>>(SA{csD, elD, offD, e1D, nullptr}, SA{csD, elD, offD, e1D, nullptr});
  k_p1<<<g1, Tb, 0, stream>>>(PA{A1, nullptr, offD, peD, pmnD, pmxD}, PA{A1, nullptr, offD, peD, pmnD, pmxD});
  t_m8<<<t1, Tb, 0, stream>>>(MA{peD, pmnD, pmxD, nullptr, eiD, MvD}, MA{peD, pmnD, pmxD, nullptr, eiD, MvD});
  k_p2<<<g1, Tb, 0, stream>>>(QA{A1, nullptr, eiD, MvD, psD}, QA{A1, nullptr, eiD, MvD, psD});
  t_red8<<<t1, Tb, 0, stream>>>(RA{psD, rdvD, 1}, RA{psD, rdvD, 1});
  k_ln<<<g1, Tb, 0, stream>>>(
      LA{A1, nullptr, e1D, nullptr, nullptr, eiD, MvD, rdvD, dec_ng + Dd, dec_nb + Dd, nullptr, nullptr, peD, pmnD, pmxD, 1},
      LA{A1, nullptr, e1D, nullptr, nullptr, eiD, MvD, rdvD, dec_ng + Dd, dec_nb + Dd, nullptr, nullptr, peD, pmnD, pmxD, 1});

  // ===== dec cross-2 =====
  t_m8<<<t1, Tb, 0, stream>>>(MA{peD, pmnD, pmxD, ectx, eiD, MvD}, MA{peD, pmnD, pmxD, ectx, eiD, MvD});
  k_p2<<<g1, Tb, 0, stream>>>(QA{A1, nullptr, eiD, MvD, psD}, QA{A1, nullptr, eiD, MvD, psD});
  t_red8<<<t1, Tb, 0, stream>>>(RA{psD, rdvD, 1}, RA{psD, rdvD, 1});
  // final LN: output tensor never read -> skip store; emit only colsum partials (csD -> k_final)
  k_ln<<<g1, Tb, 0, stream>>>(
      LA{A1, nullptr, nullptr, nullptr, v2, eiD, MvD, rdvD, dec_tg + Dd, dec_tb + Dd, csD, nullptr, nullptr, nullptr, nullptr, 0},
      LA{A1, nullptr, nullptr, nullptr, v2, eiD, MvD, rdvD, dec_tg + Dd, dec_tb + Dd, csD, nullptr, nullptr, nullptr, nullptr, 0});

  // ===== classifier (reduces csD directly) =====
  k_final<<<Bb, Tb, 0, stream>>>(csD, Wc, bc, out);
}

// Round 9
// 421.605 us; speedup vs baseline: 11.4015x; 1.1016x over previous
//
#include <hip/hip_runtime.h>
#include <math.h>

namespace {

constexpr int Bb = 8;
constexpr int Ss = 2048;
constexpr int Dd = 1024;
constexpr int D4 = Dd / 4;        // float4 per row
constexpr int NC = 128;           // s-chunks
constexpr int Sc2 = Ss / NC;      // 16 rows per chunk
constexpr int Tb = 256;
constexpr int SEG = 8;            // segments per column in tiny reducers
constexpr int CPS = NC / SEG;     // 16 chunks per segment
constexpr float INV_SCALE = 0.03125f;  // 1/sqrt(1024)
constexpr float BIG = 3.0e38f;

// branch-free erf, Abramowitz-Stegun 7.1.26, |abs err| <= 1.5e-7
__device__ __forceinline__ float fast_erf(float z) {
  float az = fabsf(z);
  float t = __builtin_amdgcn_rcpf(fmaf(0.3275911f, az, 1.0f));
  float p = fmaf(1.061405429f, t, -1.453152027f);
  p = fmaf(p, t, 1.421413741f);
  p = fmaf(p, t, -0.284496736f);
  p = fmaf(p, t, 0.254829592f);
  p *= t;
  float e = __expf(-az * az);
  float r = fmaf(-p, e, 1.0f);
  return copysignf(r, z);
}
// gelu(x, exact) + 1
__device__ __forceinline__ float fm_act(float x) {
  return fmaf(0.5f * x, 1.0f + fast_erf(x * 0.70710678118654752f), 1.0f);
}

__device__ __forceinline__ float4 f4(float v) { return make_float4(v, v, v, v); }
__device__ __forceinline__ float4 add4(float4 a, float4 b) {
  return make_float4(a.x + b.x, a.y + b.y, a.z + b.z, a.w + b.w);
}
__device__ __forceinline__ float4 mul4(float4 a, float4 b) {
  return make_float4(a.x * b.x, a.y * b.y, a.z * b.z, a.w * b.w);
}
__device__ __forceinline__ float4 fma4(float4 a, float4 b, float4 c) {
  return make_float4(fmaf(a.x, b.x, c.x), fmaf(a.y, b.y, c.y), fmaf(a.z, b.z, c.z), fmaf(a.w, b.w, c.w));
}
__device__ __forceinline__ float4 min4(float4 a, float4 b) {
  return make_float4(fminf(a.x, b.x), fminf(a.y, b.y), fminf(a.z, b.z), fminf(a.w, b.w));
}
__device__ __forceinline__ float4 max4(float4 a, float4 b) {
  return make_float4(fmaxf(a.x, b.x), fmaxf(a.y, b.y), fmaxf(a.z, b.z), fmaxf(a.w, b.w));
}
__device__ __forceinline__ float4 fm4(float4 x) {
  return make_float4(fm_act(x.x), fm_act(x.y), fm_act(x.z), fm_act(x.w));
}
__device__ __forceinline__ float4 ld4(const float* p, size_t j4) {
  return reinterpret_cast<const float4*>(p)[j4];
}
__device__ __forceinline__ void st4(float* p, size_t j4, float4 v) {
  reinterpret_cast<float4*>(p)[j4] = v;
}
__device__ __forceinline__ float4 pexp4(float4 ei, float4 qf, float4 M) {
  return make_float4(__expf(fmaf(ei.x, qf.x, -M.x)), __expf(fmaf(ei.y, qf.y, -M.y)),
                     __expf(fmaf(ei.z, qf.z, -M.z)), __expf(fmaf(ei.w, qf.w, -M.w)));
}

__device__ __forceinline__ float blockSum(float v) {
  __shared__ float wsm[Tb / 64];
  for (int off = 32; off > 0; off >>= 1) v += __shfl_down(v, off, 64);
  const int lane = threadIdx.x & 63;
  const int w = threadIdx.x >> 6;
  __syncthreads();
  if (lane == 0) wsm[w] = v;
  __syncthreads();
  return wsm[0] + wsm[1] + wsm[2] + wsm[3];
}

// ---------- arg structs (z-mergeable kernels pick by blockIdx.z) ----------
struct GA { const int* tok; float* X; float* cs; float* el; };
struct SA { const float* cs; const float* el; float* off; float* e; float* last; };
struct PA { const float* X; const float* qs; const float* off; float* pe; float* pmn; float* pmx; };
struct MA { const float* pe; const float* pmn; const float* pmx; const float* k2; float* ei; float* Mv; };
struct QA { const float* X; const float* qs; const float* ei; const float* Mv; float* ps; };
struct RA { const float* pp; float* outv; int recip; };
struct LA { float* X; const float* qs; const float* vs; const float* rs; const float* ml;
            const float* ei; const float* Mv; const float* rdv; const float* g; const float* bt;
            float* cs; float* el; float* xe; float* xn; float* xx; int wout; };

// ---------- big column-pass kernels: grid(NC, B, nz), 256 thr, thread t = float4 at d=4t ----------

// gather emb rows + chunk colsums + local gds partial
__global__ __launch_bounds__(Tb) void k_gather(GA a0, GA a1, const float* __restrict__ emb) {
  const GA a = (blockIdx.z == 0) ? a0 : a1;
  const int t = threadIdx.x, c = blockIdx.x, b = blockIdx.y;
  const int* tp = a.tok + b * Ss + c * Sc2;
  float4* xp = reinterpret_cast<float4*>(a.X) + ((size_t)(b * Ss + c * Sc2)) * D4 + t;
  const float4* ep = reinterpret_cast<const float4*>(emb);
  float4 run = f4(0.f), e = f4(0.f);
#pragma unroll
  for (int i = 0; i < Sc2; ++i) {
    float4 v = ep[(size_t)tp[i] * D4 + t];
    xp[(size_t)i * D4] = v;
    run = add4(run, v);
    e = fma4(v, run, e);
  }
  const size_t idx = ((size_t)b * NC + c) * D4 + t;
  st4(a.cs, idx, run);
  st4(a.el, idx, e);
}

// self-attn p1: ctx from off + running sum; partial ecol & qf min/max per chunk
__global__ __launch_bounds__(Tb) void k_p1(PA a0, PA a1) {
  const PA a = (blockIdx.z == 0) ? a0 : a1;
  const int t = threadIdx.x, c = blockIdx.x, b = blockIdx.y;
  const size_t idx = ((size_t)b * NC + c) * D4 + t;
  float4 run = ld4(a.off, idx);
  const float4 q4 = a.qs ? ld4(a.qs, (size_t)b * D4 + t) : f4(1.f);
  const float4* xp = reinterpret_cast<const float4*>(a.X) + ((size_t)(b * Ss + c * Sc2)) * D4 + t;
  float4 e = f4(0.f), mn = f4(BIG), mx = f4(0.f);
#pragma unroll
  for (int i = 0; i < Sc2; ++i) {
    float4 x = xp[(size_t)i * D4];
    run = add4(run, x);
    float4 qf = fm4(mul4(q4, x));
    float4 kf = fm4(run);
    e = fma4(qf, kf, e);
    mn = min4(mn, qf);
    mx = max4(mx, qf);
  }
  st4(a.pe, idx, e);
  st4(a.pmn, idx, mn);
  st4(a.pmx, idx, mx);
}

// p2: partial sumexp per chunk (self [qs] and cross [qs=null])
__global__ __launch_bounds__(Tb) void k_p2(QA a0, QA a1) {
  const QA a = (blockIdx.z == 0) ? a0 : a1;
  const int t = threadIdx.x, c = blockIdx.x, b = blockIdx.y;
  const size_t j4 = (size_t)b * D4 + t;
  const float4 q4 = a.qs ? ld4(a.qs, j4) : f4(1.f);
  const float4 e4 = ld4(a.ei, j4);
  const float4 M4 = ld4(a.Mv, j4);
  const float4* xp = reinterpret_cast<const float4*>(a.X) + ((size_t)(b * Ss + c * Sc2)) * D4 + t;
  float4 s = f4(0.f);
#pragma unroll
  for (int i = 0; i < Sc2; ++i) {
    float4 x = xp[(size_t)i * D4];
    float4 qf = fm4(mul4(q4, x));
    s = add4(s, pexp4(e4, qf, M4));
  }
  st4(a.ps, ((size_t)b * NC + c) * D4 + t, s);
}

// fused softmax-apply + residual + LayerNorm (in place, store optional via wout),
// optional chunk colsum/gds partials, optional cross-attn qf partials of the output.
__global__ __launch_bounds__(Tb) void k_ln(LA a0, LA a1) {
  const LA a = (blockIdx.z == 0) ? a0 : a1;
  __shared__ float red[Sc2][Tb];
  __shared__ float mu_s[Sc2], inv_s[Sc2];
  const int t = threadIdx.x, c = blockIdx.x, b = blockIdx.y;
  float4* xp = reinterpret_cast<float4*>(a.X) + ((size_t)(b * Ss + c * Sc2)) * D4 + t;
  const size_t j4 = (size_t)b * D4 + t;
  const float4 e4 = ld4(a.ei, j4), M4 = ld4(a.Mv, j4), rv4 = ld4(a.rdv, j4);
  const float4 q4 = a.qs ? ld4(a.qs, j4) : f4(1.f);
  const float4 vs4 = a.vs ? ld4(a.vs, j4) : f4(1.f);
  const float4 ml4 = a.ml ? ld4(a.ml, j4) : f4(1.f);
  const float4 rs4 = a.rs ? ld4(a.rs, j4) : f4(1.f);
  float4 vals[Sc2];
#pragma unroll
  for (int i = 0; i < Sc2; ++i) {
    float4 x = xp[(size_t)i * D4];
    float4 qf = fm4(mul4(q4, x));
    float4 p = mul4(pexp4(e4, qf, M4), rv4);
    float4 v = a.ml ? mul4(p, ml4) : mul4(p, mul4(vs4, x));
    float4 val = add4(v, mul4(rs4, x));
    vals[i] = val;
    red[i][t] = val.x + val.y + val.z + val.w;
  }
  __syncthreads();
  const int lane = t & 63, w = t >> 6;
#pragma unroll
  for (int rr = 0; rr < Sc2 / 4; ++rr) {
    const int row = w * (Sc2 / 4) + rr;
    float s = red[row][lane] + red[row][lane + 64] + red[row][lane + 128] + red[row][lane + 192];
    for (int off = 32; off > 0; off >>= 1) s += __shfl_down(s, off, 64);
    if (lane == 0) mu_s[row] = s * (1.0f / Dd);
  }
  __syncthreads();
#pragma unroll
  for (int i = 0; i < Sc2; ++i) {
    const float m = mu_s[i];
    float4 vv = vals[i];
    float aa = vv.x - m, b2 = vv.y - m, c2 = vv.z - m, d2 = vv.w - m;
    red[i][t] = aa * aa + b2 * b2 + c2 * c2 + d2 * d2;
  }
  __syncthreads();
#pragma unroll
  for (int rr = 0; rr < Sc2 / 4; ++rr) {
    const int row = w * (Sc2 / 4) + rr;
    float s = red[row][lane] + red[row][lane + 64] + red[row][lane + 128] + red[row][lane + 192];
    for (int off = 32; off > 0; off >>= 1) s += __shfl_down(s, off, 64);
    if (lane == 0) inv_s[row] = rsqrtf(s * (1.0f / Dd) + 1e-5f);
  }
  __syncthreads();
  const float4 g4 = ld4(a.g, t), b4 = ld4(a.bt, t);
  float4 run = f4(0.f), e = f4(0.f);
  float4 xs = f4(0.f), xmn = f4(BIG), xmx = f4(0.f);
#pragma unroll
  for (int i = 0; i < Sc2; ++i) {
    const float m = mu_s[i], inv = inv_s[i];
    float4 vv = vals[i];
    float4 y;
    y.x = fmaf((vv.x - m) * inv, g4.x, b4.x);
    y.y = fmaf((vv.y - m) * inv, g4.y, b4.y);
    y.z = fmaf((vv.z - m) * inv, g4.z, b4.z);
    y.w = fmaf((vv.w - m) * inv, g4.w, b4.w);
    if (a.wout) xp[(size_t)i * D4] = y;
    if (a.cs) {
      run = add4(run, y);
      if (a.el) e = fma4(y, run, e);
    }
    if (a.xe) {
      float4 qfy = fm4(y);
      xs = add4(xs, qfy);
      xmn = min4(xmn, qfy);
      xmx = max4(xmx, qfy);
    }
  }
  const size_t idx = ((size_t)b * NC + c) * D4 + t;
  if (a.cs) st4(a.cs, idx, run);
  if (a.el) st4(a.el, idx, e);
  if (a.xe) {
    st4(a.xe, idx, xs);
    st4(a.xn, idx, xmn);
    st4(a.xx, idx, xmx);
  }
}

// ---------- tiny reducers: grid(BD/32, 1, nz), 256 thr = 32 columns x 8 segments ----------

__global__ __launch_bounds__(Tb) void t_scan8(SA a0, SA a1) {
  const SA a = (blockIdx.z == 0) ? a0 : a1;
  __shared__ float lds[SEG][32];
  const int tid = threadIdx.x;
  const int jl = tid & 31, seg = tid >> 5;
  const int j = blockIdx.x * 32 + jl;
  const int b = j >> 10, d = j & 1023;
  const size_t base = (size_t)b * NC * Dd + d;
  float s = 0.f;
#pragma unroll 8
  for (int i = 0; i < CPS; ++i) s += a.cs[base + (size_t)(seg * CPS + i) * Dd];
  lds[seg][jl] = s;
  __syncthreads();
  float o = 0.f;
#pragma unroll
  for (int g2 = 0; g2 < SEG; ++g2) { float v = lds[g2][jl]; o += (g2 < seg) ? v : 0.f; }
  __syncthreads();
  float run = o, e = 0.f;
#pragma unroll 8
  for (int i = 0; i < CPS; ++i) {
    const size_t k = base + (size_t)(seg * CPS + i) * Dd;
    float cv = a.cs[k];
    a.off[k] = run;
    e += a.el[k] + run * cv;
    run += cv;
  }
  lds[seg][jl] = e;
  __syncthreads();
  if (seg == 0) {
    float et = 0.f;
#pragma unroll
    for (int g2 = 0; g2 < SEG; ++g2) et += lds[g2][jl];
    a.e[j] = et;
  }
  if (a.last && seg == SEG - 1) a.last[j] = run;
}

// reduce p1/xq partials -> ei, Mv. k2 non-null => cross (ec = fm(k2)*colsum)
__global__ __launch_bounds__(Tb) void t_m8(MA a0, MA a1) {
  const MA a = (blockIdx.z == 0) ? a0 : a1;
  __shared__ float le[SEG][32], lmn[SEG][32], lmx[SEG][32];
  const int tid = threadIdx.x;
  const int jl = tid & 31, seg = tid >> 5;
  const int j = blockIdx.x * 32 + jl;
  const int b = j >> 10, d = j & 1023;
  const size_t base = (size_t)b * NC * Dd + d;
  float ec = 0.f, mn = BIG, mx = 0.f;
#pragma unroll 8
  for (int i = 0; i < CPS; ++i) {
    const size_t k = base + (size_t)(seg * CPS + i) * Dd;
    ec += a.pe[k];
    mn = fminf(mn, a.pmn[k]);
    mx = fmaxf(mx, a.pmx[k]);
  }
  le[seg][jl] = ec; lmn[seg][jl] = mn; lmx[seg][jl] = mx;
  __syncthreads();
  if (seg == 0) {
#pragma unroll
    for (int g2 = 1; g2 < SEG; ++g2) {
      ec += le[g2][jl];
      mn = fminf(mn, lmn[g2][jl]);
      mx = fmaxf(mx, lmx[g2][jl]);
    }
    if (a.k2) ec *= fm_act(a.k2[j]);
    const float e2 = ec * INV_SCALE;
    a.ei[j] = e2;
    a.Mv[j] = (ec >= 0.f) ? e2 * mx : e2 * mn;
  }
}

// reduce partials -> sum (recip=0) or 1/sum (recip=1)
__global__ __launch_bounds__(Tb) void t_red8(RA a0, RA a1) {
  const RA a = (blockIdx.z == 0) ? a0 : a1;
  __shared__ float lds[SEG][32];
  const int tid = threadIdx.x;
  const int jl = tid & 31, seg = tid >> 5;
  const int j = blockIdx.x * 32 + jl;
  const int b = j >> 10, d = j & 1023;
  const size_t base = (size_t)b * NC * Dd + d;
  float s = 0.f;
#pragma unroll 8
  for (int i = 0; i < CPS; ++i) s += a.pp[base + (size_t)(seg * CPS + i) * Dd];
  lds[seg][jl] = s;
  __syncthreads();
  if (seg == 0) {
#pragma unroll
    for (int g2 = 1; g2 < SEG; ++g2) s += lds[g2][jl];
    a.outv[j] = a.recip ? 1.0f / s : s;
  }
}

// out[b,o] = (pooled[b,:]/S) @ Wc + bc
__global__ __launch_bounds__(Tb) void k_final(const float* __restrict__ pooled, const float* __restrict__ Wc,
    const float* __restrict__ bc, float* __restrict__ out) {
  const int b = blockIdx.x, t = threadIdx.x;
  float4 acc = ld4(pooled, (size_t)b * D4 + t);
  float4 w0 = ld4(Wc, 2 * t), w1 = ld4(Wc, 2 * t + 1);
  float s0 = acc.x * w0.x + acc.y * w0.z + acc.z * w1.x + acc.w * w1.z;
  float s1 = acc.x * w0.y + acc.y * w0.w + acc.z * w1.y + acc.w * w1.w;
  s0 = blockSum(s0);
  s1 = blockSum(s1);
  if (t == 0) {
    out[b * 2 + 0] = s0 * (1.0f / Ss) + bc[0];
    out[b * 2 + 1] = s1 * (1.0f / Ss) + bc[1];
  }
}

}  // namespace

extern "C" void kernel_launch(void* const* d_in, const int* in_sizes, int n_in,
                              void* d_out, int out_size, void* d_ws, size_t ws_size,
                              hipStream_t stream) {
  (void)in_sizes; (void)n_in; (void)out_size; (void)ws_size;
  const int* src = (const int*)d_in[0];
  const int* trg = (const int*)d_in[1];
  const float* emb = (const float*)d_in[2];
  const float* enc_g = (const float*)d_in[3];
  const float* enc_b = (const float*)d_in[4];
  const float* dec_ng = (const float*)d_in[5];
  const float* dec_nb = (const float*)d_in[6];
  const float* dec_tg = (const float*)d_in[7];
  const float* dec_tb = (const float*)d_in[8];
  const float* Wc = (const float*)d_in[9];
  const float* bc = (const float*)d_in[10];
  float* out = (float*)d_out;

  float* ws = (float*)d_ws;
  const size_t TEN = (size_t)Bb * Ss * Dd;      // 16.7M floats
  const size_t MM = (size_t)Bb * NC * Dd;       // 1M floats (4 MB)
  float* A0 = ws;                                // encoder tensor
  float* A1 = A0 + TEN;                          // decoder tensor
  float* p = A1 + TEN;
  float* csE = p; p += MM;  float* elE = p; p += MM;  float* offE = p; p += MM;
  float* peE = p; p += MM;  float* pmnE = p; p += MM; float* pmxE = p; p += MM;
  float* psE = p; p += MM;
  float* csD = p; p += MM;  float* elD = p; p += MM;  float* offD = p; p += MM;
  float* peD = p; p += MM;  float* pmnD = p; p += MM; float* pmxD = p; p += MM;
  float* psD = p; p += MM;
  const int BD = Bb * Dd;
  float* e0E = p; p += BD;  float* e1E = p; p += BD;
  float* e0D = p; p += BD;  float* e1D = p; p += BD;
  float* eiE = p; p += BD;  float* MvE = p; p += BD;  float* rdvE = p; p += BD;
  float* eiD = p; p += BD;  float* MvD = p; p += BD;  float* rdvD = p; p += BD;
  float* ectx = p; p += BD; float* v2 = p; p += BD;   float* pooled = p; p += BD;

  const dim3 g2(NC, Bb, 2), g1(NC, Bb, 1);
  const dim3 t2(BD / 32, 1, 2), t1(BD / 32, 1, 1);

  // ===== L1 stage: encoder L1 || decoder L1 self (independent, z-merged) =====
  k_gather<<<g2, Tb, 0, stream>>>(GA{src, A0, csE, elE}, GA{trg, A1, csD, elD}, emb);
  t_scan8<<<t2, Tb, 0, stream>>>(SA{csE, elE, offE, e0E, nullptr}, SA{csD, elD, offD, e0D, nullptr});
  k_p1<<<g2, Tb, 0, stream>>>(PA{A0, e0E, offE, peE, pmnE, pmxE}, PA{A1, e0D, offD, peD, pmnD, pmxD});
  t_m8<<<t2, Tb, 0, stream>>>(MA{peE, pmnE, pmxE, nullptr, eiE, MvE}, MA{peD, pmnD, pmxD, nullptr, eiD, MvD});
  k_p2<<<g2, Tb, 0, stream>>>(QA{A0, e0E, eiE, MvE, psE}, QA{A1, e0D, eiD, MvD, psD});
  t_red8<<<t2, Tb, 0, stream>>>(RA{psE, rdvE, 1}, RA{psD, rdvD, 1});
  // enc L1 LN (emits cs/el for enc L2 scan); dec L1 self LN (emits cross-attn qf partials)
  k_ln<<<g2, Tb, 0, stream>>>(
      LA{A0, e0E, e0E, e0E, nullptr, eiE, MvE, rdvE, enc_g, enc_b, csE, elE, nullptr, nullptr, nullptr, 1},
      LA{A1, e0D, e0D, e0D, nullptr, eiD, MvD, rdvD, dec_ng, dec_nb, nullptr, nullptr, peD, pmnD, pmxD, 1});

  // ===== enc L2 scan (produces ectx, the only cross-attn K) =====
  t_scan8<<<t1, Tb, 0, stream>>>(SA{csE, elE, offE, e1E, ectx}, SA{csE, elE, offE, e1E, ectx});
  k_p1<<<g1, Tb, 0, stream>>>(PA{A0, nullptr, offE, peE, pmnE, pmxE}, PA{A0, nullptr, offE, peE, pmnE, pmxE});

  // ===== enc L2 self || dec cross-1 (z-merged) =====
  t_m8<<<t2, Tb, 0, stream>>>(MA{peE, pmnE, pmxE, nullptr, eiE, MvE}, MA{peD, pmnD, pmxD, ectx, eiD, MvD});
  k_p2<<<g2, Tb, 0, stream>>>(QA{A0, nullptr, eiE, MvE, psE}, QA{A1, nullptr, eiD, MvD, psD});
  t_red8<<<t2, Tb, 0, stream>>>(RA{psE, rdvE, 1}, RA{psD, rdvD, 1});
  // enc L2 LN: output tensor never read -> skip store; emit only colsum partials (v2)
  k_ln<<<g1, Tb, 0, stream>>>(
      LA{A0, nullptr, e1E, nullptr, nullptr, eiE, MvE, rdvE, enc_g + Dd, enc_b + Dd, csE, nullptr, nullptr, nullptr, nullptr, 0},
      LA{A0, nullptr, e1E, nullptr, nullptr, eiE, MvE, rdvE, enc_g + Dd, enc_b + Dd, csE, nullptr, nullptr, nullptr, nullptr, 0});
  t_red8<<<t1, Tb, 0, stream>>>(RA{csE, v2, 0}, RA{csE, v2, 0});  // v2 = colsum(enc_out)

  // ===== dec cross-1 LN (needs v2) =====
  k_ln<<<g1, Tb, 0, stream>>>(
      LA{A1, nullptr, nullptr, nullptr, v2, eiD, MvD, rdvD, dec_tg, dec_tb, csD, elD, nullptr, nullptr, nullptr, 1},
      LA{A1, nullptr, nullptr, nullptr, v2, eiD, MvD, rdvD, dec_tg, dec_tb, csD, elD, nullptr, nullptr, nullptr, 1});

  // ===== dec L2 self =====
  t_scan8<<<t1, Tb, 0, stream>>>(SA{csD, elD, offD, e1D, nullptr}, SA{csD, elD, offD, e1D, nullptr});
  k_p1<<<g1, Tb, 0, stream>>>(PA{A1, nullptr, offD, peD, pmnD, pmxD}, PA{A1, nullptr, offD, peD, pmnD, pmxD});
  t_m8<<<t1, Tb, 0, stream>>>(MA{peD, pmnD, pmxD, nullptr, eiD, MvD}, MA{peD, pmnD, pmxD, nullptr, eiD, MvD});
  k_p2<<<g1, Tb, 0, stream>>>(QA{A1, nullptr, eiD, MvD, psD}, QA{A1, nullptr, eiD, MvD, psD});
  t_red8<<<t1, Tb, 0, stream>>>(RA{psD, rdvD, 1}, RA{psD, rdvD, 1});
  k_ln<<<g1, Tb, 0, stream>>>(
      LA{A1, nullptr, e1D, nullptr, nullptr, eiD, MvD, rdvD, dec_ng + Dd, dec_nb + Dd, nullptr, nullptr, peD, pmnD, pmxD, 1},
      LA{A1, nullptr, e1D, nullptr, nullptr, eiD, MvD, rdvD, dec_ng + Dd, dec_nb + Dd, nullptr, nullptr, peD, pmnD, pmxD, 1});

  // ===== dec cross-2 =====
  t_m8<<<t1, Tb, 0, stream>>>(MA{peD, pmnD, pmxD, ectx, eiD, MvD}, MA{peD, pmnD, pmxD, ectx, eiD, MvD});
  k_p2<<<g1, Tb, 0, stream>>>(QA{A1, nullptr, eiD, MvD, psD}, QA{A1, nullptr, eiD, MvD, psD});
  t_red8<<<t1, Tb, 0, stream>>>(RA{psD, rdvD, 1}, RA{psD, rdvD, 1});
  // final LN: output tensor never read -> skip store; emit only colsum partials (csD)
  k_ln<<<g1, Tb, 0, stream>>>(
      LA{A1, nullptr, nullptr, nullptr, v2, eiD, MvD, rdvD, dec_tg + Dd, dec_tb + Dd, csD, nullptr, nullptr, nullptr, nullptr, 0},
      LA{A1, nullptr, nullptr, nullptr, v2, eiD, MvD, rdvD, dec_tg + Dd, dec_tb + Dd, csD, nullptr, nullptr, nullptr, nullptr, 0});

  // ===== pooled + classifier =====
  t_red8<<<t1, Tb, 0, stream>>>(RA{csD, pooled, 0}, RA{csD, pooled, 0});
  k_final<<<Bb, Tb, 0, stream>>>(pooled, Wc, bc, out);
}